// Round 17
// baseline (190.586 us; speedup 1.0000x reference)
//
#include <hip/hip_runtime.h>

typedef __bf16 bf16_t;
typedef __bf16 bf16x4_t __attribute__((ext_vector_type(4)));
typedef __bf16 bf16x8_t __attribute__((ext_vector_type(8)));
typedef float f32x16_t __attribute__((ext_vector_type(16)));

#define AS_G(p) ((const __attribute__((address_space(1))) void*)(p))
#define AS_L(p) ((__attribute__((address_space(3))) void*)(p))
// R11 post-mortem: vmcnt drain before a barrier publishing global_load_lds
// data must be EXPLICIT (__syncthreads alone was replay-flaky).
#define DRAIN_VM() asm volatile("s_waitcnt vmcnt(0)" ::: "memory")

// ---------------------------------------------------------------------------
// Weight repack (oc, ic, ky, kx) fp32 -> bf16 in MFMA B-fragment order:
//   frag f = th*16 + kc*4 + nt*2 + wc,  th = t*2+hk  (frag = 1024 B, lane*16B)
//   lane -> oc = wc*64 + nt*32 + (lane&31); ic = (hk*8 + kc*2 + (lane>>5))*8 + e
// ---------------------------------------------------------------------------
__device__ __forceinline__ void repack_body(const float* __restrict__ w,
                                            bf16_t* __restrict__ wt2,
                                            int o) {
  int e = o & 7;
  int lane = (o >> 3) & 63;
  int f = o >> 9;
  int wc = f & 1;
  int nt = (f >> 1) & 1;
  int kc = (f >> 2) & 3;
  int hk = (f >> 4) & 1;
  int t = f >> 5;
  int oc = wc * 64 + nt * 32 + (lane & 31);
  int ic = (hk * 8 + kc * 2 + (lane >> 5)) * 8 + e;
  wt2[o] = (bf16_t)w[((size_t)oc * 128 + ic) * 9 + t];
}

// ---------------------------------------------------------------------------
// DWT body (explicit block coords): in fp32 (B,32,2h,2w) ->
//   sub bf16 NHWC (B,h,w,128) ci=4c+q  [+ ll fp32 (B,32,h,w)]
// ---------------------------------------------------------------------------
__device__ __forceinline__ void dwt_body(const float* __restrict__ in,
                                         bf16_t* __restrict__ sub,
                                         float* __restrict__ llout,
                                         int h, int w, int bi, int i, int j0,
                                         bf16_t* lds) {
  const int tid = threadIdx.x;
  const int j = tid & 63;
  const int cg = tid >> 6;
  const int jg = j0 + j;
  const bool jok = jg < w;
  const int H2 = h * 2, W2 = w * 2;
  for (int c = cg; c < 32; c += 4) {
    float va = 0.f, vb = 0.f, vc = 0.f, vd = 0.f;
    if (jok) {
      const float2* p0 = (const float2*)(in + ((size_t)(bi * 32 + c) * H2 + 2 * i) * W2);
      const float2* p1 = (const float2*)(in + ((size_t)(bi * 32 + c) * H2 + 2 * i + 1) * W2);
      float2 r0 = p0[jg];
      float2 r1 = p1[jg];
      va = r0.x; vb = r0.y; vc = r1.x; vd = r1.y;
    }
    float ll = (va + vb + vc + vd) * 0.5f;
    float lh = (va - vb + vc - vd) * 0.5f;
    float hl = (va + vb - vc - vd) * 0.5f;
    float hh = (va - vb - vc + vd) * 0.5f;
    bf16x4_t q;
    q.x = (bf16_t)ll; q.y = (bf16_t)lh; q.z = (bf16_t)hl; q.w = (bf16_t)hh;
    *(bf16x4_t*)(&lds[j * 132 + c * 4]) = q;
    if (llout != nullptr && jok)
      llout[((size_t)(bi * 32 + c) * h + i) * w + jg] = ll;
  }
  __syncthreads();
  const size_t obase = ((size_t)bi * h + i) * w;
  for (int it = 0; it < 8; ++it) {
    int flat = it * 256 + tid;
    int jj = flat >> 5;
    int c4 = flat & 31;
    if (j0 + jj < w) {
      bf16x4_t q = *(const bf16x4_t*)(&lds[jj * 132 + c4 * 4]);
      *(bf16x4_t*)(sub + ((obase + j0 + jj) << 7) + c4 * 4) = q;
    }
  }
}

// ---------------------------------------------------------------------------
// STAGE 1 (one dispatch, 2296 blocks -- all independent):
//   [0,448)     dwt1 direct from x (4x4 Haar avgs; bit-identical to ll0+dwt1)
//   [448,2240)  sub0 production (x -> sub0 bf16 NHWC), old dwt0 blocks
//   [2240,2296) weight repack slab
// ---------------------------------------------------------------------------
__global__ __launch_bounds__(256) void stage1_kernel(
    const float* __restrict__ x, bf16_t* __restrict__ sub0,
    bf16_t* __restrict__ sub1, float* __restrict__ ll1,
    const float* __restrict__ wsrc, bf16_t* __restrict__ wt2) {
  __shared__ __align__(16) bf16_t lds[64 * 132];
  const int B = blockIdx.x;
  const int tid = threadIdx.x;
  if (B >= 2240) {                         // repack: 56 blocks
    int bid = B - 2240;
    for (int o = bid * 256 + tid; o < 147456; o += 56 * 256)
      repack_body(wsrc, wt2, o);
    return;
  }
  if (B >= 448) {                          // sub0: decode (2,112,8)
    int r = B - 448;                       // 0..1791
    int bx = r & 1;
    int rr = r >> 1;
    int i = rr % 112;
    int bi = rr / 112;
    dwt_body(x, sub0, nullptr, 112, 112, bi, i, bx * 64, lds);
    return;
  }
  // dwt1 direct from x: bi = B/56, i = B%56, h=w=56
  const int bi = B / 56;
  const int i = B % 56;
  const int j = tid & 63;
  const int cg = tid >> 6;
  const int h = 56, w = 56;
  const bool jok = j < w;
  for (int c = cg; c < 32; c += 4) {
    float va = 0.f, vb = 0.f, vc = 0.f, vd = 0.f;
    if (jok) {
      const float* base = x + ((size_t)(bi * 32 + c) * 224 + 4 * i) * 224;
      float4 p0 = ((const float4*)(base))[j];
      float4 p1 = ((const float4*)(base + 224))[j];
      float4 p2 = ((const float4*)(base + 448))[j];
      float4 p3 = ((const float4*)(base + 672))[j];
      va = (p0.x + p0.y + p1.x + p1.y) * 0.5f;
      vb = (p0.z + p0.w + p1.z + p1.w) * 0.5f;
      vc = (p2.x + p2.y + p3.x + p3.y) * 0.5f;
      vd = (p2.z + p2.w + p3.z + p3.w) * 0.5f;
    }
    float ll = (va + vb + vc + vd) * 0.5f;
    float lh = (va - vb + vc - vd) * 0.5f;
    float hl = (va + vb - vc - vd) * 0.5f;
    float hh = (va - vb - vc + vd) * 0.5f;
    bf16x4_t q;
    q.x = (bf16_t)ll; q.y = (bf16_t)lh; q.z = (bf16_t)hl; q.w = (bf16_t)hh;
    *(bf16x4_t*)(&lds[j * 132 + c * 4]) = q;
    if (jok)
      ll1[((size_t)(bi * 32 + c) * h + i) * w + j] = ll;
  }
  __syncthreads();
  const size_t obase = ((size_t)bi * h + i) * w;
  for (int it = 0; it < 8; ++it) {
    int flat = it * 256 + tid;
    int jj = flat >> 5;
    int c4 = flat & 31;
    if (jj < w) {
      bf16x4_t q = *(const bf16x4_t*)(&lds[jj * 132 + c4 * 4]);
      *(bf16x4_t*)(sub1 + ((obase + jj) << 7) + c4 * 4) = q;
    }
  }
}

// dwt for level 2 (ll1 -> sub2)
__global__ __launch_bounds__(256) void dwt_kernel(const float* __restrict__ in,
                                                  bf16_t* __restrict__ sub,
                                                  float* __restrict__ llout,
                                                  int h, int w) {
  __shared__ __align__(16) bf16_t lds[64 * 132];
  dwt_body(in, sub, llout, h, w, blockIdx.z, blockIdx.y, blockIdx.x * 64, lds);
}

// ---------------------------------------------------------------------------
// Fused conv 3x3 (pad1, 128ic -> 64oc-HALF, MFMA 32x32x16 bf16) + IDWT epi.
// R12/R14 core VERBATIM (proven replay-stable, ~57us for 1568 blocks). All
// call sites now pass nll=nullptr: output is the RAW 0.5*idwt contribution
// (nll/bias folded in by the fixup pass via IDWT linearity).
// LDS = 23040 halo + 16384 Bdbuf = 39424 B -> 4 blocks/CU.
// ---------------------------------------------------------------------------
__device__ __forceinline__ void conv_idwt_tile(
    const bf16_t* __restrict__ sub, const bf16_t* __restrict__ wt2,
    float* __restrict__ out, int h, int w, int bi, int y0, int x0, int och,
    uint4* smemV) {
  char* haloS = (char*)smemV;                      // 180 px * 128 B = 23040 B
  char* Bbuf = (char*)smemV + 23040;               // 2 x 8192 B
  float* scr = (float*)((char*)smemV + 23040);     // epilogue alias over Bbuf
  const int tid = threadIdx.x;
  const size_t img_base = (size_t)bi * h * w;

  const int lane = tid & 63;
  const int wv = tid >> 6;                 // wave id (0..3)
  const int m = lane & 31;                 // A-operand m index / D col (oc32)
  const int hw_ = lane >> 5;               // half-wave: k offset hw_*8
  const int il = wv * 2 + (m >> 4);        // local pixel row 0..7
  const int jl = m & 15;
  const int pixA = il * 18 + jl;

  f32x16_t acc[2] = {};

  for (int hk = 0; hk < 2; ++hk) {
    if (hk) __syncthreads();               // pass-0 readers done before overwrite
    // ---- stage halo half: 180 px x 8 chunks of 16B, zero-filled borders ----
    for (int it = 0; it < 6; ++it) {
      int flat = it * 256 + tid;           // 1440 slots
      int pix = flat >> 3;
      int ch = flat & 7;
      if (pix < 180) {
        int r = pix / 18;
        int c = pix - r * 18;
        int gy = y0 + r - 1;
        int gx = x0 + c - 1;
        uint4 v = make_uint4(0u, 0u, 0u, 0u);
        if ((unsigned)gy < (unsigned)h && (unsigned)gx < (unsigned)w)
          v = *(const uint4*)(sub + ((img_base + (size_t)gy * w + gx) << 7) +
                              ((hk * 8 + ch) << 3));
        *(uint4*)(haloS + (pix << 7) + ((ch ^ (pix & 7)) << 4)) = v;
      }
    }
    // ---- stage B for t=0 of this hk into buf 0 (2 frag-DMAs per wave) ----
    {
      const int th0 = hk;                  // th = 0*2 + hk
#pragma unroll
      for (int q = 0; q < 2; ++q) {
        const bf16_t* srcp = wt2 + (((th0 << 4) + (wv << 2) + (q << 1) + och) << 9) + (lane << 3);
        __builtin_amdgcn_global_load_lds(AS_G(srcp),
            AS_L(Bbuf + (((wv << 1) + q) << 10)), 16, 0, 0);
      }
    }
    DRAIN_VM();                            // B(0) DMA landed in LDS
    __syncthreads();                       // halo + B(0) published

    int cur = 0;
    for (int t = 0; t < 9; ++t) {
      if (t < 8) {                         // fire-and-forget next tap's B
        const int thn = ((t + 1) << 1) + hk;
#pragma unroll
        for (int q = 0; q < 2; ++q) {
          const bf16_t* srcp = wt2 + (((thn << 4) + (wv << 2) + (q << 1) + och) << 9) + (lane << 3);
          __builtin_amdgcn_global_load_lds(AS_G(srcp),
              AS_L(Bbuf + ((cur ^ 1) << 13) + (((wv << 1) + q) << 10)), 16, 0, 0);
        }
      }
      const int ky = t / 3;
      const int kx = t - ky * 3;
      const int pix0 = pixA + ky * 18 + kx;
      const int s0 = pix0 & 7;
      const char* hp0 = haloS + (pix0 << 7);
      const char* bp = Bbuf + (cur << 13) + (lane << 4);
#pragma unroll
      for (int kc = 0; kc < 4; ++kc) {
        bf16x8_t b0 = *(const bf16x8_t*)(bp + ((kc << 1) << 10));
        bf16x8_t b1 = *(const bf16x8_t*)(bp + (((kc << 1) + 1) << 10));
        const int cidx = kc * 2 + hw_;     // 16B chunk within the 64-ic half
        bf16x8_t a0 = *(const bf16x8_t*)(hp0 + ((cidx ^ s0) << 4));
        acc[0] = __builtin_amdgcn_mfma_f32_32x32x16_bf16(a0, b0, acc[0], 0, 0, 0);
        acc[1] = __builtin_amdgcn_mfma_f32_32x32x16_bf16(a0, b1, acc[1], 0, 0, 0);
      }
      DRAIN_VM();                          // B(t+1) DMA landed in LDS
      __syncthreads();                     // my B(t)/halo reads done; publish B(t+1)
      cur ^= 1;
    }
  }

  // ---- IDWT epilogue (raw): 4 phases of 16 oc over scr[128][17] ----
  // D layout (m74/m101): row = (reg&3)+8*(reg>>2)+4*hw_ (0..31), col(oc32)=m;
  // pixel px = wv*32 + row (row-major 8x16 tile). Writes o = 0.5*e only.
  const int W2 = w * 2;
  const int H2 = h * 2;
  const int mh_t = m >> 4;                 // which 16-oc half this lane holds
  const int mm = m & 15;
  const int kw = mm >> 2;                  // channel-within-16 (write side)
  const int sw = mm & 3;                   // subband q

#pragma unroll
  for (int ph = 0; ph < 4; ++ph) {
    const int nt = ph >> 1;
    const int mh = ph & 1;
    if (ph) __syncthreads();               // prior read phase done
    if (mh_t == mh) {
#pragma unroll
      for (int reg = 0; reg < 16; ++reg) {
        int row = (reg & 3) + ((reg >> 2) << 3) + (hw_ << 2);
        int px = wv * 32 + row;            // 0..127
        scr[px * 17 + (kw << 2) + sw] = acc[nt][reg];
      }
    }
    __syncthreads();
    // read phase: 4 ch x 8 rows x 8 col-pairs x 2 dy = 512 tasks -> 2 iters
#pragma unroll
    for (int it = 0; it < 2; ++it) {
      int idx = it * 256 + tid;
      int ox4 = idx & 7;
      int dy = (idx >> 3) & 1;
      int row = (idx >> 4) & 7;
      int k = (idx >> 7) & 3;
      int gy = y0 + row;
      int gx = x0 + ox4 * 2;
      if (gy >= h || gx >= w) continue;
      int p0 = row * 16 + ox4 * 2;
      int p1 = p0 + 1;
      float4 sa = *(const float4*)(&scr[p0 * 17 + (k << 2)]);
      float4 sb = *(const float4*)(&scr[p1 * 17 + (k << 2)]);
      float sg = dy ? -1.f : 1.f;
      float e0 = sa.x + sa.y + sg * (sa.z + sa.w);
      float e1 = sa.x - sa.y + sg * (sa.z - sa.w);
      float e2 = sb.x + sb.y + sg * (sb.z + sb.w);
      float e3 = sb.x - sb.y + sg * (sb.z - sb.w);
      int ch = och * 16 + nt * 8 + mh * 4 + k;   // output channel 0..31
      float* op = out + ((size_t)(bi * 32 + ch) * H2 + 2 * gy + dy) * W2 + 2 * gx;
      float4 o;
      o.x = 0.5f * e0; o.y = 0.5f * e1; o.z = 0.5f * e2; o.w = 0.5f * e3;
      *(float4*)op = o;
    }
  }
}

// ---------------------------------------------------------------------------
// MEGACONV: ALL conv+idwt blocks in one dispatch (2144 blocks, independent
// since the nll chain is deferred to the fixup pass):
//   [0,1568)    level 0: sub0 -> out (raw idwt)
//   [1568,2016) level 1: sub1 -> nll1raw
//   [2016,2144) level 2: sub2 -> nll2
// ---------------------------------------------------------------------------
__global__ __launch_bounds__(256, 4) void megaconv_kernel(
    const bf16_t* __restrict__ sub0, const bf16_t* __restrict__ sub1,
    const bf16_t* __restrict__ sub2, const bf16_t* __restrict__ wt2,
    float* __restrict__ out, float* __restrict__ nll1raw,
    float* __restrict__ nll2) {
  __shared__ uint4 smemV[2464];            // 39424 B
  const int B = blockIdx.x;
  if (B < 1568) {                          // level 0: decode (14,14,8)
    int xx = B % 14;
    int rem = B / 14;
    int yy = rem % 14;
    int bi = rem / 14;
    conv_idwt_tile(sub0, wt2, out, 112, 112, bi, yy * 8, (xx >> 1) * 16,
                   xx & 1, smemV);
    return;
  }
  if (B < 2016) {                          // level 1 (56x56)
    int lb = B - 1568;
    int och = lb & 1;
    int q = lb >> 1;
    int bx = q & 3;
    int r = q >> 2;
    int by = r % 7;
    int bi = r / 7;
    conv_idwt_tile(sub1, wt2, nll1raw, 56, 56, bi, by * 8, bx * 16, och, smemV);
    return;
  }
  {                                        // level 2 (28x28)
    int lb = B - 2016;
    int och = lb & 1;
    int q = lb >> 1;
    int bx = q & 1;
    int r = q >> 1;
    int by = r & 3;
    int bi = r >> 2;
    conv_idwt_tile(sub2, wt2, nll2, 28, 28, bi, by * 8, bx * 16, och, smemV);
  }
}

// ---------------------------------------------------------------------------
// FIXUP: out += 0.5*nll1raw(up2) + 0.25*nll2(up4) + bias  (IDWT-linearity
// fold of the deeper levels; arithmetic matches the old fused epilogue:
// o = 0.5*e + 0.5*(nll1 + 0.5*nll2up) + bias). Coalesced float4 RMW.
// 3,211,264 threads: g -> (b, c, oy, q); out cols 4q..4q+3.
// ---------------------------------------------------------------------------
__global__ __launch_bounds__(256) void fixup_kernel(
    float* __restrict__ out, const float* __restrict__ nll1,
    const float* __restrict__ nll2, const float* __restrict__ bias) {
  int g = blockIdx.x * 256 + threadIdx.x;  // 0..3211263
  int q = g % 56;
  int r1 = g / 56;
  int oy = r1 % 224;
  int r2 = r1 / 224;
  int c = r2 & 31;
  int b = r2 >> 5;
  float2 n1 = *(const float2*)(nll1 + ((size_t)(b * 32 + c) * 112 + (oy >> 1)) * 112 + 2 * q);
  float n2 = nll2[((size_t)(b * 32 + c) * 56 + (oy >> 2)) * 56 + q];
  float bv = bias[c];
  float add0 = 0.5f * n1.x + 0.25f * n2 + bv;
  float add1 = 0.5f * n1.y + 0.25f * n2 + bv;
  float* op = out + ((size_t)(b * 32 + c) * 224 + oy) * 224 + 4 * q;
  float4 v = *(float4*)op;
  v.x += add0; v.y += add0; v.z += add1; v.w += add1;
  *(float4*)op = v;
}

// ---------------------------------------------------------------------------
// Workspace layout (bytes, peak 66,125,824):
//   wt2  @ 0           (294,912)
//   sub0 @ 294,912     (25,690,112)
//   sub1 @ 25,985,024  (6,422,528)
//   sub2 @ 32,407,552  (1,605,632)
//   ll1  @ 46,858,240  (3,211,264)
//   nll2 @ 50,069,504  (3,211,264)
//   nll1 @ 53,280,768  (12,845,056)  -> end 66,125,824
// ---------------------------------------------------------------------------
extern "C" void kernel_launch(void* const* d_in, const int* in_sizes, int n_in,
                              void* d_out, int out_size, void* d_ws, size_t ws_size,
                              hipStream_t stream) {
  if (ws_size < 66125824u) return;

  const float* x = (const float*)d_in[0];
  const float* weight = (const float*)d_in[1];
  const float* bias = (const float*)d_in[2];
  float* out = (float*)d_out;
  char* ws = (char*)d_ws;

  bf16_t* wt2 = (bf16_t*)(ws);
  bf16_t* sub0 = (bf16_t*)(ws + 294912);
  bf16_t* sub1 = (bf16_t*)(ws + 25985024);
  bf16_t* sub2 = (bf16_t*)(ws + 32407552);
  float* ll1 = (float*)(ws + 46858240);
  float* nll2 = (float*)(ws + 50069504);
  float* nll1 = (float*)(ws + 53280768);

  // stage 1: dwt1-from-x + sub0 production + weight repack (all independent)
  stage1_kernel<<<2296, 256, 0, stream>>>(x, sub0, sub1, ll1, weight, wt2);
  // dwt2: ll1 -> sub2
  dwt_kernel<<<dim3(1, 28, 8), 256, 0, stream>>>(ll1, sub2, nullptr, 28, 28);
  // ALL conv+idwt blocks in one dispatch (levels independent via linearity)
  megaconv_kernel<<<2144, 256, 0, stream>>>(sub0, sub1, sub2, wt2, out, nll1, nll2);
  // fixup: out += 0.5*nll1up + 0.25*nll2up + bias
  fixup_kernel<<<12544, 256, 0, stream>>>(out, nll1, nll2, bias);
}